// Round 1
// baseline (254.247 us; speedup 1.0000x reference)
//
#include <hip/hip_runtime.h>
#include <cstdint>
#include <cstddef>

// DeepFM Criteo forward, MI355X/gfx950.
// Pipeline: split(emb2,w1,w2 -> bf16 hi/lo planes) ; FM(y1+y2 fp32) ;
// gemm1 (gather-A 3-pass bf16-split MFMA, relu, split-store h1) ;
// gemm2 (3-pass split MFMA, relu, f32 h2) ; final (dot w3 + sigmoid).

#define B_ROWS   16384
#define NSPARSE  26
#define NDENSE   13
#define EMBD     128
#define HID      256
#define K1       (NSPARSE*EMBD)   // 3328
#define VOCAB    4823

typedef unsigned short ushort_t;
typedef __attribute__((ext_vector_type(8))) short bf16x8;   // 8 bf16 = 4 VGPR (A/B frag)
typedef __attribute__((ext_vector_type(4))) float f32x4;    // C/D frag

// ---- bf16 helpers (RNE round, self-contained bit ops) ----
__device__ __forceinline__ ushort_t f32_bf16(float x) {
    unsigned u = __builtin_bit_cast(unsigned, x);
    u += 0x7fffu + ((u >> 16) & 1u);
    return (ushort_t)(u >> 16);
}
__device__ __forceinline__ float bf16_f32(ushort_t h) {
    return __builtin_bit_cast(float, ((unsigned)h) << 16);
}

// async global->LDS, 16B per lane. LDS dest must be uniform_base + lane*16.
__device__ __forceinline__ void gl2lds16(const void* g, void* l) {
    __builtin_amdgcn_global_load_lds(
        (const __attribute__((address_space(1))) void*)g,
        (__attribute__((address_space(3))) void*)l, 16, 0, 0);
}

// ---------------------------------------------------------------------------
// split: fp32 -> (hi bf16, lo bf16) planes, vectorized float4 / ushort4
// ---------------------------------------------------------------------------
__global__ void split_kernel(const float* __restrict__ src,
                             ushort_t* __restrict__ hi, ushort_t* __restrict__ lo,
                             int n4) {
    int i = blockIdx.x * blockDim.x + threadIdx.x;
    if (i >= n4) return;
    float4 x = ((const float4*)src)[i];
    union { ushort_t u[4]; uint2 v; } H, L;
    float xs[4] = {x.x, x.y, x.z, x.w};
#pragma unroll
    for (int j = 0; j < 4; ++j) {
        ushort_t h = f32_bf16(xs[j]);
        H.u[j] = h;
        L.u[j] = f32_bf16(xs[j] - bf16_f32(h));
    }
    ((uint2*)hi)[i] = H.v;
    ((uint2*)lo)[i] = L.v;
}

// ---------------------------------------------------------------------------
// FM: y12[b] = dense.fm_w + sum emb1[idx] + 0.5*sum(s^2 - ss)   (all fp32 exact)
// one wave per row; lane owns dims {lane, lane+64}
// ---------------------------------------------------------------------------
__global__ __launch_bounds__(256) void fm_kernel(
    const float* __restrict__ dense, const int* __restrict__ sidx,
    const float* __restrict__ emb1, const float* __restrict__ emb2,
    const float* __restrict__ fm_w, float* __restrict__ y12) {
    int b = blockIdx.x * 4 + (threadIdx.x >> 6);
    int lane = threadIdx.x & 63;
    const int* I = sidx + b * NSPARSE;
    float s0 = 0.f, ss0 = 0.f, s1 = 0.f, ss1 = 0.f;
#pragma unroll
    for (int f = 0; f < NSPARSE; ++f) {
        const float* e = emb2 + (size_t)I[f] * EMBD;
        float v0 = e[lane], v1 = e[lane + 64];
        s0 += v0; ss0 += v0 * v0;
        s1 += v1; ss1 += v1 * v1;
    }
    float r = 0.5f * ((s0 * s0 - ss0) + (s1 * s1 - ss1));
    if (lane < NDENSE)  r += dense[b * NDENSE + lane] * fm_w[lane];
    if (lane < NSPARSE) r += emb1[I[lane]];
#pragma unroll
    for (int o = 32; o; o >>= 1) r += __shfl_xor(r, o, 64);
    if (lane == 0) y12[b] = r;
}

// ---------------------------------------------------------------------------
// GEMM: C[M,256] = relu(A[M,KDIM] @ W[256,KDIM]^T), 3-pass bf16-split.
// 128x128 tile, 4 waves of 64x64, BK=32, 16x16x32 MFMA, 2-phase prefetch.
// GATHER: A row k-slice comes from emb2 via sidx (flat never materialized).
// LDS quarter-swizzle: slot (row,qs) holds data-quarter qd = qs ^ (row&3);
// applied on the global SOURCE (linear LDS dest) and on the ds_read address.
// ---------------------------------------------------------------------------
template <int KDIM, bool GATHER, int EPI>
__global__ __launch_bounds__(256) void gemm_kernel(
    const ushort_t* __restrict__ Ah, const ushort_t* __restrict__ Al,
    const ushort_t* __restrict__ Bh, const ushort_t* __restrict__ Bl,
    const int* __restrict__ sidx,
    float* __restrict__ Cf, ushort_t* __restrict__ Chi, ushort_t* __restrict__ Clo) {
    constexpr int NT = KDIM / 32;
    __shared__ ushort_t lsA[2][2][128 * 32];   // [buf][hi/lo]
    __shared__ ushort_t lsB[2][2][128 * 32];
    __shared__ int sI[GATHER ? 128 * NSPARSE : 1];

    const int t = threadIdx.x;
    const int bm = blockIdx.x, bn = blockIdx.y;

    if constexpr (GATHER) {
        const int* g = sidx + (size_t)bm * 128 * NSPARSE;   // contiguous block of indices
        for (int i = t; i < 128 * NSPARSE; i += 256) sI[i] = g[i];
        __syncthreads();
    }

    auto stage = [&](int buf, int kt) {
#pragma unroll
        for (int j = 0; j < 2; ++j) {          // A tile: 128x32 bf16 = 8KB = 2 issues/plane
            int s   = j * 256 + t;
            int row = s >> 2;
            int qd  = (s & 3) ^ (row & 3);
            size_t off;
            if constexpr (GATHER) {
                int f = kt >> 2;                       // field (BK=32 never crosses field)
                int d = ((kt & 3) * 32) + qd * 8;
                off = (size_t)sI[row * NSPARSE + f] * EMBD + d;
            } else {
                off = (size_t)(bm * 128 + row) * KDIM + kt * 32 + qd * 8;
            }
            gl2lds16(Ah + off, &lsA[buf][0][s * 8]);
            gl2lds16(Al + off, &lsA[buf][1][s * 8]);
        }
#pragma unroll
        for (int j = 0; j < 2; ++j) {          // B tile: 128x32
            int s   = j * 256 + t;
            int row = s >> 2;
            int qd  = (s & 3) ^ (row & 3);
            size_t off = (size_t)(bn * 128 + row) * KDIM + kt * 32 + qd * 8;
            gl2lds16(Bh + off, &lsB[buf][0][s * 8]);
            gl2lds16(Bl + off, &lsB[buf][1][s * 8]);
        }
    };

    f32x4 acc[4][4] = {};
    const int l = t & 63, w = t >> 6;
    const int wr = w >> 1, wc = w & 1;          // wave -> 64x64 sub-tile
    const int lrow = l & 15, lq = l >> 4;
    const int qs = lq ^ (lrow & 3);             // swizzled quarter for ds_read

    stage(0, 0);
    __syncthreads();                             // buf0 ready (drains vmcnt)
    int buf = 0;
    for (int kt = 0; kt < NT; ++kt) {
        if (kt + 1 < NT) stage(buf ^ 1, kt + 1); // prefetch overlaps compute
        bf16x8 aH[4], aL[4], bH[4], bL[4];
#pragma unroll
        for (int m = 0; m < 4; ++m) {
            int o = (wr * 64 + m * 16 + lrow) * 32 + qs * 8;
            aH[m] = *(const bf16x8*)&lsA[buf][0][o];
            aL[m] = *(const bf16x8*)&lsA[buf][1][o];
        }
#pragma unroll
        for (int n = 0; n < 4; ++n) {
            int o = (wc * 64 + n * 16 + lrow) * 32 + qs * 8;
            bH[n] = *(const bf16x8*)&lsB[buf][0][o];
            bL[n] = *(const bf16x8*)&lsB[buf][1][o];
        }
#pragma unroll
        for (int m = 0; m < 4; ++m)
#pragma unroll
            for (int n = 0; n < 4; ++n) {
                acc[m][n] = __builtin_amdgcn_mfma_f32_16x16x32_bf16(aL[m], bH[n], acc[m][n], 0, 0, 0);
                acc[m][n] = __builtin_amdgcn_mfma_f32_16x16x32_bf16(aH[m], bL[n], acc[m][n], 0, 0, 0);
                acc[m][n] = __builtin_amdgcn_mfma_f32_16x16x32_bf16(aH[m], bH[n], acc[m][n], 0, 0, 0);
            }
        __syncthreads();                         // staged buf^1 landed; reads of buf done
        buf ^= 1;
    }

    // epilogue: C/D layout col=lane&15, row=(lane>>4)*4+reg  [m89-verified]
#pragma unroll
    for (int m = 0; m < 4; ++m)
#pragma unroll
        for (int n = 0; n < 4; ++n) {
            int col = bn * 128 + wc * 64 + n * 16 + lrow;
#pragma unroll
            for (int r = 0; r < 4; ++r) {
                int row = bm * 128 + wr * 64 + m * 16 + lq * 4 + r;
                float h = fmaxf(acc[m][n][r], 0.f);
                if constexpr (EPI == 0) {
                    ushort_t hh = f32_bf16(h);
                    Chi[(size_t)row * HID + col] = hh;
                    Clo[(size_t)row * HID + col] = f32_bf16(h - bf16_f32(hh));
                } else {
                    Cf[(size_t)row * HID + col] = h;
                }
            }
        }
}

// ---------------------------------------------------------------------------
// final: out[b] = sigmoid(y12[b] + h2[b,:].w3)
// ---------------------------------------------------------------------------
__global__ __launch_bounds__(256) void final_kernel(
    const float* __restrict__ h2, const float* __restrict__ w3,
    const float* __restrict__ y12, float* __restrict__ out) {
    int b = blockIdx.x * 4 + (threadIdx.x >> 6);
    int lane = threadIdx.x & 63;
    const float* hr = h2 + (size_t)b * HID;
    float a = hr[lane]       * w3[lane]
            + hr[lane + 64]  * w3[lane + 64]
            + hr[lane + 128] * w3[lane + 128]
            + hr[lane + 192] * w3[lane + 192];
#pragma unroll
    for (int o = 32; o; o >>= 1) a += __shfl_xor(a, o, 64);
    if (lane == 0) {
        float z = y12[b] + a;
        out[b] = 1.f / (1.f + __expf(-z));
    }
}

// ---------------------------------------------------------------------------
extern "C" void kernel_launch(void* const* d_in, const int* in_sizes, int n_in,
                              void* d_out, int out_size, void* d_ws, size_t ws_size,
                              hipStream_t stream) {
    const float* dense = (const float*)d_in[0];
    const int*   sidx  = (const int*)d_in[1];
    const float* emb1  = (const float*)d_in[2];
    const float* emb2  = (const float*)d_in[3];
    const float* fm_w  = (const float*)d_in[4];
    const float* w1    = (const float*)d_in[5];
    const float* w2    = (const float*)d_in[6];
    const float* w3    = (const float*)d_in[7];
    float* out = (float*)d_out;

    // workspace carve (all 256B-aligned), ~38 MB total
    char* p = (char*)d_ws;
    auto carve = [&](size_t bytes) { void* r = (void*)p; p += (bytes + 255) & ~(size_t)255; return r; };
    ushort_t* e2h = (ushort_t*)carve((size_t)VOCAB * EMBD * 2);
    ushort_t* e2l = (ushort_t*)carve((size_t)VOCAB * EMBD * 2);
    ushort_t* w1h = (ushort_t*)carve((size_t)HID * K1 * 2);
    ushort_t* w1l = (ushort_t*)carve((size_t)HID * K1 * 2);
    ushort_t* w2h = (ushort_t*)carve((size_t)HID * HID * 2);
    ushort_t* w2l = (ushort_t*)carve((size_t)HID * HID * 2);
    ushort_t* h1h = (ushort_t*)carve((size_t)B_ROWS * HID * 2);
    ushort_t* h1l = (ushort_t*)carve((size_t)B_ROWS * HID * 2);
    float*    h2  = (float*)carve((size_t)B_ROWS * HID * 4);
    float*    y12 = (float*)carve((size_t)B_ROWS * 4);

    int n4;
    n4 = VOCAB * EMBD / 4;
    split_kernel<<<(n4 + 255) / 256, 256, 0, stream>>>(emb2, e2h, e2l, n4);
    n4 = HID * K1 / 4;
    split_kernel<<<(n4 + 255) / 256, 256, 0, stream>>>(w1, w1h, w1l, n4);
    n4 = HID * HID / 4;
    split_kernel<<<(n4 + 255) / 256, 256, 0, stream>>>(w2, w2h, w2l, n4);

    fm_kernel<<<B_ROWS / 4, 256, 0, stream>>>(dense, sidx, emb1, emb2, fm_w, y12);

    gemm_kernel<K1, true, 0><<<dim3(B_ROWS / 128, HID / 128), 256, 0, stream>>>(
        e2h, e2l, w1h, w1l, sidx, nullptr, h1h, h1l);

    gemm_kernel<HID, false, 1><<<dim3(B_ROWS / 128, HID / 128), 256, 0, stream>>>(
        h1h, h1l, w2h, w2l, nullptr, h2, nullptr, nullptr);

    final_kernel<<<B_ROWS / 4, 256, 0, stream>>>(h2, w3, y12, out);
}

// Round 2
// 226.528 us; speedup vs baseline: 1.1224x; 1.1224x over previous
//
#include <hip/hip_runtime.h>
#include <cstdint>
#include <cstddef>

// DeepFM Criteo forward, MI355X/gfx950 — round 2.
// Algorithmic restructure: layer-1 GEMM factored through the vocab:
//   P[v, f*256+h] = sum_d emb2[v,d] * w1[h, f*128+d]   (one 4864x6656x128 GEMM)
//   h1[b,:]       = relu( sum_f P[idx[b,f], f*256 : f*256+256] )   (gather-sum)
// 8.2 GF instead of 27.9 GF for layer 1; batch side becomes L3-BW streaming.
// FM (y1+y2) fused into the gather kernel. All accumulation fp32; GEMMs use
// 3-pass bf16-split MFMA (fp32-equivalent accuracy).

#define B_ROWS   16384
#define NSPARSE  26
#define NDENSE   13
#define EMBD     128
#define HID      256
#define K1       (NSPARSE*EMBD)   // 3328
#define VOCAB    4823
#define PAD_V    4864             // 38 * 128
#define NP       (NSPARSE*HID)    // 6656  (P row length)

typedef unsigned short ushort_t;
typedef __attribute__((ext_vector_type(8))) short bf16x8;   // MFMA A/B frag
typedef __attribute__((ext_vector_type(4))) float f32x4;    // MFMA C/D frag

// ---- bf16 helpers (RNE) ----
__device__ __forceinline__ ushort_t f32_bf16(float x) {
    unsigned u = __builtin_bit_cast(unsigned, x);
    u += 0x7fffu + ((u >> 16) & 1u);
    return (ushort_t)(u >> 16);
}
__device__ __forceinline__ float bf16_f32(ushort_t h) {
    return __builtin_bit_cast(float, ((unsigned)h) << 16);
}

// async global->LDS, 16B/lane; LDS dest = uniform base + lane*16 (linear).
__device__ __forceinline__ void gl2lds16(const void* g, void* l) {
    __builtin_amdgcn_global_load_lds(
        (const __attribute__((address_space(1))) void*)g,
        (__attribute__((address_space(3))) void*)l, 16, 0, 0);
}

// ---------------------------------------------------------------------------
// split: fp32 -> (hi bf16, lo bf16) planes
// ---------------------------------------------------------------------------
__global__ void split_kernel(const float* __restrict__ src,
                             ushort_t* __restrict__ hi, ushort_t* __restrict__ lo,
                             int n4) {
    int i = blockIdx.x * blockDim.x + threadIdx.x;
    if (i >= n4) return;
    float4 x = ((const float4*)src)[i];
    union { ushort_t u[4]; uint2 v; } H, L;
    float xs[4] = {x.x, x.y, x.z, x.w};
#pragma unroll
    for (int j = 0; j < 4; ++j) {
        ushort_t h = f32_bf16(xs[j]);
        H.u[j] = h;
        L.u[j] = f32_bf16(xs[j] - bf16_f32(h));
    }
    ((uint2*)hi)[i] = H.v;
    ((uint2*)lo)[i] = L.v;
}

// ---------------------------------------------------------------------------
// splitT: w1[h, f*128+d] -> B''[(f*256+h)*128 + d], hi/lo split. Coalesced both sides.
// ---------------------------------------------------------------------------
__global__ void splitT_kernel(const float* __restrict__ w1,
                              ushort_t* __restrict__ hi, ushort_t* __restrict__ lo,
                              int n4) {
    int i = blockIdx.x * blockDim.x + threadIdx.x;   // one float4 of B''
    if (i >= n4) return;
    int c    = i & 31;        // float4 index within 128-d row
    int rowp = i >> 5;        // f*256 + h
    int f = rowp >> 8, h = rowp & 255;
    float4 x = ((const float4*)w1)[h * (K1 / 4) + f * 32 + c];
    union { ushort_t u[4]; uint2 v; } H, L;
    float xs[4] = {x.x, x.y, x.z, x.w};
#pragma unroll
    for (int j = 0; j < 4; ++j) {
        ushort_t hh = f32_bf16(xs[j]);
        H.u[j] = hh;
        L.u[j] = f32_bf16(xs[j] - bf16_f32(hh));
    }
    ((uint2*)hi)[i] = H.v;
    ((uint2*)lo)[i] = L.v;
}

// ---------------------------------------------------------------------------
// GEMM: C[M,N] = (relu?)(A[M,KDIM] @ W[N,KDIM]^T), 3-pass bf16-split MFMA.
// 128x128 tile, 4 waves of 64x64, BK=32, 2-phase prefetch, 64KB LDS (2 blk/CU).
// Quarter-swizzle: slot (row,qs) holds quarter qd = qs ^ (row&3), applied on
// the global SOURCE (linear gl2lds dest) and on the ds_read address.
// Epilogue transposes through LDS (reusing tile memory) -> coalesced dwordx4.
// EPI: 1 = relu + f32 store, 3 = plain f32 store.
// ---------------------------------------------------------------------------
template <int KDIM, int EPI>
__global__ __launch_bounds__(256) void gemm_kernel(
    const ushort_t* __restrict__ Ah, const ushort_t* __restrict__ Al,
    const ushort_t* __restrict__ Bh, const ushort_t* __restrict__ Bl,
    float* __restrict__ Cf, int ldc) {
    constexpr int NT = KDIM / 32;
    __shared__ union {
        ushort_t ab[2][2][2][128 * 32];   // [A/B][buf][hi/lo]
        float    t[128 * 128];            // epilogue transpose tile
    } sm;

    const int t = threadIdx.x;
    const int bm = blockIdx.x, bn = blockIdx.y;

    auto stage = [&](int buf, int kt) {
#pragma unroll
        for (int j = 0; j < 2; ++j) {
            int s   = j * 256 + t;
            int row = s >> 2;
            int qd  = (s & 3) ^ (row & 3);
            size_t offA = (size_t)(bm * 128 + row) * KDIM + kt * 32 + qd * 8;
            gl2lds16(Ah + offA, &sm.ab[0][buf][0][s * 8]);
            gl2lds16(Al + offA, &sm.ab[0][buf][1][s * 8]);
            size_t offB = (size_t)(bn * 128 + row) * KDIM + kt * 32 + qd * 8;
            gl2lds16(Bh + offB, &sm.ab[1][buf][0][s * 8]);
            gl2lds16(Bl + offB, &sm.ab[1][buf][1][s * 8]);
        }
    };

    f32x4 acc[4][4] = {};
    const int l = t & 63, w = t >> 6;
    const int wr = w >> 1, wc = w & 1;
    const int lrow = l & 15, lq = l >> 4;
    const int qs = lq ^ (lrow & 3);

    stage(0, 0);
    __syncthreads();
    int buf = 0;
    for (int kt = 0; kt < NT; ++kt) {
        if (kt + 1 < NT) stage(buf ^ 1, kt + 1);
        bf16x8 aH[4], aL[4], bH[4], bL[4];
#pragma unroll
        for (int m = 0; m < 4; ++m) {
            int o = (wr * 64 + m * 16 + lrow) * 32 + qs * 8;
            aH[m] = *(const bf16x8*)&sm.ab[0][buf][0][o];
            aL[m] = *(const bf16x8*)&sm.ab[0][buf][1][o];
        }
#pragma unroll
        for (int n = 0; n < 4; ++n) {
            int o = (wc * 64 + n * 16 + lrow) * 32 + qs * 8;
            bH[n] = *(const bf16x8*)&sm.ab[1][buf][0][o];
            bL[n] = *(const bf16x8*)&sm.ab[1][buf][1][o];
        }
#pragma unroll
        for (int m = 0; m < 4; ++m)
#pragma unroll
            for (int n = 0; n < 4; ++n) {
                acc[m][n] = __builtin_amdgcn_mfma_f32_16x16x32_bf16(aL[m], bH[n], acc[m][n], 0, 0, 0);
                acc[m][n] = __builtin_amdgcn_mfma_f32_16x16x32_bf16(aH[m], bL[n], acc[m][n], 0, 0, 0);
                acc[m][n] = __builtin_amdgcn_mfma_f32_16x16x32_bf16(aH[m], bH[n], acc[m][n], 0, 0, 0);
            }
        __syncthreads();   // staged buf^1 landed; reads of buf done
        buf ^= 1;
    }

    // ---- epilogue via LDS transpose (tile memory now free) ----
    // C/D frag layout: col = lane&15, row = (lane>>4)*4 + reg  [m89-verified]
#pragma unroll
    for (int m = 0; m < 4; ++m)
#pragma unroll
        for (int n = 0; n < 4; ++n) {
            int col = wc * 64 + n * 16 + lrow;
#pragma unroll
            for (int r = 0; r < 4; ++r) {
                int row = wr * 64 + m * 16 + lq * 4 + r;
                float v = acc[m][n][r];
                if constexpr (EPI == 1) v = fmaxf(v, 0.f);
                sm.t[row * 128 + col] = v;
            }
        }
    __syncthreads();
    const int c = t & 31, r0 = t >> 5;
#pragma unroll
    for (int k = 0; k < 16; ++k) {
        int row = r0 + k * 8;
        float4 v4 = *(const float4*)&sm.t[row * 128 + c * 4];
        *(float4*)&Cf[(size_t)(bm * 128 + row) * ldc + bn * 128 + c * 4] = v4;
    }
}

// ---------------------------------------------------------------------------
// gather_fm: h1[b,:] = relu(sum_f P[idx[b,f], f*256:+256])  (split-stored bf16)
//            y12[b]  = dense.fm_w + sum emb1[idx] + 0.5*sum(s^2-ss)
// one wave per row; lane owns h {4l..4l+3} and dims {l, l+64}.
// ---------------------------------------------------------------------------
__global__ __launch_bounds__(256) void gather_fm_kernel(
    const float* __restrict__ P, const float* __restrict__ dense,
    const int* __restrict__ sidx, const float* __restrict__ emb1,
    const float* __restrict__ emb2, const float* __restrict__ fm_w,
    ushort_t* __restrict__ h1h, ushort_t* __restrict__ h1l,
    float* __restrict__ y12) {
    int b = blockIdx.x * 4 + (threadIdx.x >> 6);
    int l = threadIdx.x & 63;
    int myI = (l < NSPARSE) ? sidx[b * NSPARSE + l] : 0;

    float4 hacc = {0.f, 0.f, 0.f, 0.f};
    float s0 = 0.f, ss0 = 0.f, s1 = 0.f, ss1 = 0.f;
#pragma unroll
    for (int f = 0; f < NSPARSE; ++f) {
        int v = __shfl(myI, f, 64);
        float4 pv = *(const float4*)(P + (size_t)v * NP + f * HID + 4 * l);
        const float* e = emb2 + (size_t)v * EMBD;
        float e0 = e[l], e1 = e[l + 64];
        hacc.x += pv.x; hacc.y += pv.y; hacc.z += pv.z; hacc.w += pv.w;
        s0 += e0; ss0 += e0 * e0;
        s1 += e1; ss1 += e1 * e1;
    }
    // split-store h1
    float hs[4] = {fmaxf(hacc.x, 0.f), fmaxf(hacc.y, 0.f),
                   fmaxf(hacc.z, 0.f), fmaxf(hacc.w, 0.f)};
    union { ushort_t u[4]; uint2 v; } H, L;
#pragma unroll
    for (int j = 0; j < 4; ++j) {
        ushort_t hh = f32_bf16(hs[j]);
        H.u[j] = hh;
        L.u[j] = f32_bf16(hs[j] - bf16_f32(hh));
    }
    *(uint2*)(h1h + (size_t)b * HID + 4 * l) = H.v;
    *(uint2*)(h1l + (size_t)b * HID + 4 * l) = L.v;
    // FM scalar
    float r = 0.5f * ((s0 * s0 - ss0) + (s1 * s1 - ss1));
    if (l < NDENSE)  r += dense[b * NDENSE + l] * fm_w[l];
    if (l < NSPARSE) r += emb1[myI];
#pragma unroll
    for (int o = 32; o; o >>= 1) r += __shfl_xor(r, o, 64);
    if (l == 0) y12[b] = r;
}

// ---------------------------------------------------------------------------
// final: out[b] = sigmoid(y12[b] + h2[b,:].w3)
// ---------------------------------------------------------------------------
__global__ __launch_bounds__(256) void final_kernel(
    const float* __restrict__ h2, const float* __restrict__ w3,
    const float* __restrict__ y12, float* __restrict__ out) {
    int b = blockIdx.x * 4 + (threadIdx.x >> 6);
    int lane = threadIdx.x & 63;
    const float* hr = h2 + (size_t)b * HID;
    float a = hr[lane]       * w3[lane]
            + hr[lane + 64]  * w3[lane + 64]
            + hr[lane + 128] * w3[lane + 128]
            + hr[lane + 192] * w3[lane + 192];
#pragma unroll
    for (int o = 32; o; o >>= 1) a += __shfl_xor(a, o, 64);
    if (lane == 0) {
        float z = y12[b] + a;
        out[b] = 1.f / (1.f + __expf(-z));
    }
}

// ---------------------------------------------------------------------------
extern "C" void kernel_launch(void* const* d_in, const int* in_sizes, int n_in,
                              void* d_out, int out_size, void* d_ws, size_t ws_size,
                              hipStream_t stream) {
    const float* dense = (const float*)d_in[0];
    const int*   sidx  = (const int*)d_in[1];
    const float* emb1  = (const float*)d_in[2];
    const float* emb2  = (const float*)d_in[3];
    const float* fm_w  = (const float*)d_in[4];
    const float* w1    = (const float*)d_in[5];
    const float* w2    = (const float*)d_in[6];
    const float* w3    = (const float*)d_in[7];
    float* out = (float*)d_out;

    // workspace carve (256B-aligned), ~162 MB total
    char* p = (char*)d_ws;
    auto carve = [&](size_t bytes) { void* r = (void*)p; p += (bytes + 255) & ~(size_t)255; return r; };
    ushort_t* e2h = (ushort_t*)carve((size_t)PAD_V * EMBD * 2);
    ushort_t* e2l = (ushort_t*)carve((size_t)PAD_V * EMBD * 2);
    ushort_t* b1h = (ushort_t*)carve((size_t)NP * EMBD * 2);
    ushort_t* b1l = (ushort_t*)carve((size_t)NP * EMBD * 2);
    ushort_t* w2h = (ushort_t*)carve((size_t)HID * HID * 2);
    ushort_t* w2l = (ushort_t*)carve((size_t)HID * HID * 2);
    ushort_t* h1h = (ushort_t*)carve((size_t)B_ROWS * HID * 2);
    ushort_t* h1l = (ushort_t*)carve((size_t)B_ROWS * HID * 2);
    float*    h2  = (float*)carve((size_t)B_ROWS * HID * 4);
    float*    y12 = (float*)carve((size_t)B_ROWS * 4);
    float*    P   = (float*)carve((size_t)PAD_V * NP * 4);

    int n4;
    n4 = VOCAB * EMBD / 4;                 // fill real rows only; pad rows stay garbage (never gathered)
    split_kernel<<<(n4 + 255) / 256, 256, 0, stream>>>(emb2, e2h, e2l, n4);
    n4 = NP * EMBD / 4;
    splitT_kernel<<<(n4 + 255) / 256, 256, 0, stream>>>(w1, b1h, b1l, n4);
    n4 = HID * HID / 4;
    split_kernel<<<(n4 + 255) / 256, 256, 0, stream>>>(w2, w2h, w2l, n4);

    // P = emb2 @ B''^T   [4864 x 6656], fp32
    gemm_kernel<EMBD, 3><<<dim3(PAD_V / 128, NP / 128), 256, 0, stream>>>(
        e2h, e2l, b1h, b1l, P, NP);

    // h1 = relu(gather-sum(P)), y12 = FM
    gather_fm_kernel<<<B_ROWS / 4, 256, 0, stream>>>(
        P, dense, sidx, emb1, emb2, fm_w, h1h, h1l, y12);

    // h2 = relu(h1 @ w2^T)
    gemm_kernel<HID, 1><<<dim3(B_ROWS / 128, HID / 128), 256, 0, stream>>>(
        h1h, h1l, w2h, w2l, h2, HID);

    final_kernel<<<B_ROWS / 4, 256, 0, stream>>>(h2, w3, y12, out);
}

// Round 3
// 152.644 us; speedup vs baseline: 1.6656x; 1.4840x over previous
//
#include <hip/hip_runtime.h>
#include <cstdint>
#include <cstddef>

// DeepFM Criteo forward, MI355X/gfx950 — round 3.
// Deep path (y3) entirely bf16: P = emb2 @ B''^T stored bf16 (65 MB, L3-fit),
// single-pass bf16 MFMA GEMMs, h1/h2 bf16. FM path (y1+y2, the dominant logit
// terms) stays fp32-exact. Error budget: output abs err ~1e-5.
//   P[v, f*256+h] = sum_d emb2[v,d] * w1[h, f*128+d]     (4864x6656x128 GEMM)
//   h1[b,:]       = relu( sum_f P[idx[b,f], f*256:+256] ) (gather-sum, L3 BW)
//   h2 = relu(h1 @ w2^T); out = sigmoid(y12 + h2.w3)

#define B_ROWS   16384
#define NSPARSE  26
#define NDENSE   13
#define EMBD     128
#define HID      256
#define K1       (NSPARSE*EMBD)   // 3328
#define VOCAB    4823
#define PAD_V    4864             // 38 * 128
#define NP       (NSPARSE*HID)    // 6656 bf16 = 13312 B per P row (16B aligned)

typedef unsigned short ushort_t;
typedef __attribute__((ext_vector_type(8))) short bf16x8;      // MFMA A/B frag
typedef __attribute__((ext_vector_type(8))) unsigned short ushort8;
typedef __attribute__((ext_vector_type(4))) float f32x4;       // MFMA C/D frag

// ---- bf16 helpers (RNE) ----
__device__ __forceinline__ ushort_t f32_bf16(float x) {
    unsigned u = __builtin_bit_cast(unsigned, x);
    u += 0x7fffu + ((u >> 16) & 1u);
    return (ushort_t)(u >> 16);
}
__device__ __forceinline__ float bf16_f32(ushort_t h) {
    return __builtin_bit_cast(float, ((unsigned)h) << 16);
}

// async global->LDS, 16B/lane; LDS dest = wave-uniform base + lane*16 (linear).
__device__ __forceinline__ void gl2lds16(const void* g, void* l) {
    __builtin_amdgcn_global_load_lds(
        (const __attribute__((address_space(1))) void*)g,
        (__attribute__((address_space(3))) void*)l, 16, 0, 0);
}

// ---------------------------------------------------------------------------
// split: fp32 -> bf16, vectorized
// ---------------------------------------------------------------------------
__global__ void split_kernel(const float* __restrict__ src,
                             ushort_t* __restrict__ dst, int n4) {
    int i = blockIdx.x * blockDim.x + threadIdx.x;
    if (i >= n4) return;
    float4 x = ((const float4*)src)[i];
    union { ushort_t u[4]; uint2 v; } H;
    float xs[4] = {x.x, x.y, x.z, x.w};
#pragma unroll
    for (int j = 0; j < 4; ++j) H.u[j] = f32_bf16(xs[j]);
    ((uint2*)dst)[i] = H.v;
}

// splitT: w1[h, f*128+d] -> B''[(f*256+h)*128 + d] bf16. Coalesced both sides.
__global__ void splitT_kernel(const float* __restrict__ w1,
                              ushort_t* __restrict__ dst, int n4) {
    int i = blockIdx.x * blockDim.x + threadIdx.x;
    if (i >= n4) return;
    int c    = i & 31;        // float4 within 128-d row
    int rowp = i >> 5;        // f*256 + h
    int f = rowp >> 8, h = rowp & 255;
    float4 x = ((const float4*)w1)[h * (K1 / 4) + f * 32 + c];
    union { ushort_t u[4]; uint2 v; } H;
    float xs[4] = {x.x, x.y, x.z, x.w};
#pragma unroll
    for (int j = 0; j < 4; ++j) H.u[j] = f32_bf16(xs[j]);
    ((uint2*)dst)[i] = H.v;
}

// ---------------------------------------------------------------------------
// GEMM: C[M,N] = (relu?)(A[M,KDIM] @ W[N,KDIM]^T), single-pass bf16 MFMA.
// 128x128 tile, 4 waves of 64x64, BK=32, 2-phase prefetch, 32KB LDS.
// Quarter-swizzle: slot (row,qs) holds quarter qd = qs ^ (row&3), applied on
// the global SOURCE (linear gl2lds dest) and on the ds_read address.
// Epilogue transposes through LDS (union'd) -> coalesced 16B bf16 stores.
// ---------------------------------------------------------------------------
template <int KDIM, bool RELU>
__global__ __launch_bounds__(256) void gemm_bf16_kernel(
    const ushort_t* __restrict__ A, const ushort_t* __restrict__ Bm,
    ushort_t* __restrict__ C, int ldc) {
    constexpr int NT = KDIM / 32;
    __shared__ union {
        ushort_t ab[2][2][128 * 32];   // [buf][A/B], 32 KB
        ushort_t t[128 * 128];         // epilogue transpose tile, 32 KB
    } sm;

    const int tid = threadIdx.x;
    const int bm = blockIdx.x, bn = blockIdx.y;

    auto stage = [&](int buf, int kt) {
#pragma unroll
        for (int j = 0; j < 2; ++j) {
            int s   = j * 256 + tid;
            int row = s >> 2;
            int qd  = (s & 3) ^ (row & 3);
            size_t offA = (size_t)(bm * 128 + row) * KDIM + kt * 32 + qd * 8;
            gl2lds16(A + offA, &sm.ab[buf][0][s * 8]);
            size_t offB = (size_t)(bn * 128 + row) * KDIM + kt * 32 + qd * 8;
            gl2lds16(Bm + offB, &sm.ab[buf][1][s * 8]);
        }
    };

    f32x4 acc[4][4] = {};
    const int l = tid & 63, w = tid >> 6;
    const int wr = w >> 1, wc = w & 1;
    const int lrow = l & 15, lq = l >> 4;
    const int qs = lq ^ (lrow & 3);

    stage(0, 0);
    __syncthreads();
    int buf = 0;
    for (int kt = 0; kt < NT; ++kt) {
        if (kt + 1 < NT) stage(buf ^ 1, kt + 1);
        bf16x8 af[4], bf[4];
#pragma unroll
        for (int m = 0; m < 4; ++m)
            af[m] = *(const bf16x8*)&sm.ab[buf][0][(wr * 64 + m * 16 + lrow) * 32 + qs * 8];
#pragma unroll
        for (int n = 0; n < 4; ++n)
            bf[n] = *(const bf16x8*)&sm.ab[buf][1][(wc * 64 + n * 16 + lrow) * 32 + qs * 8];
#pragma unroll
        for (int m = 0; m < 4; ++m)
#pragma unroll
            for (int n = 0; n < 4; ++n)
                acc[m][n] = __builtin_amdgcn_mfma_f32_16x16x32_bf16(af[m], bf[n], acc[m][n], 0, 0, 0);
        __syncthreads();   // staged buf^1 landed; reads of buf done
        buf ^= 1;
    }

    // epilogue: frag (col=lane&15, row=(lane>>4)*4+reg) -> LDS -> 16B stores
#pragma unroll
    for (int m = 0; m < 4; ++m)
#pragma unroll
        for (int n = 0; n < 4; ++n) {
            int col = wc * 64 + n * 16 + lrow;
#pragma unroll
            for (int r = 0; r < 4; ++r) {
                int row = wr * 64 + m * 16 + lq * 4 + r;
                float v = acc[m][n][r];
                if constexpr (RELU) v = fmaxf(v, 0.f);
                sm.t[row * 128 + col] = f32_bf16(v);
            }
        }
    __syncthreads();
    const int r0 = tid >> 4, c16 = tid & 15;
#pragma unroll
    for (int k = 0; k < 8; ++k) {
        int row = r0 + k * 16;
        ushort8 v8 = *(const ushort8*)&sm.t[row * 128 + c16 * 8];
        *(ushort8*)&C[(size_t)(bm * 128 + row) * ldc + bn * 128 + c16 * 8] = v8;
    }
}

// ---------------------------------------------------------------------------
// gather_fm: h1[b,:] = relu(sum_f P[idx[b,f], f*256:+256])  (bf16 P, bf16 h1)
//            y12[b]  = dense.fm_w + sum emb1[idx] + 0.5*sum(s^2-ss)  (fp32)
// one wave per row; half-wave owns odd/even fields, lane li owns h 8li..8li+7
// (16B P loads); halves combined via shfl_xor(32).
// ---------------------------------------------------------------------------
__global__ __launch_bounds__(256) void gather_fm_kernel(
    const ushort_t* __restrict__ Pb, const float* __restrict__ dense,
    const int* __restrict__ sidx, const float* __restrict__ emb1,
    const float* __restrict__ emb2, const float* __restrict__ fm_w,
    ushort_t* __restrict__ h1b, float* __restrict__ y12) {
    int b = blockIdx.x * 4 + (threadIdx.x >> 6);
    int l = threadIdx.x & 63;
    int half = l >> 5, li = l & 31;
    int myI = (l < NSPARSE) ? sidx[b * NSPARSE + l] : 0;

    float acc8[8] = {};
#pragma unroll
    for (int fp = 0; fp < NSPARSE / 2; ++fp) {
        int f = fp * 2 + half;
        int v = __shfl(myI, f, 64);
        ushort8 pv = *(const ushort8*)(Pb + (size_t)v * NP + f * HID + li * 8);
#pragma unroll
        for (int j = 0; j < 8; ++j) acc8[j] += bf16_f32(pv[j]);
    }
    // FM (fp32-exact)
    float s0 = 0.f, ss0 = 0.f, s1 = 0.f, ss1 = 0.f;
#pragma unroll
    for (int f = 0; f < NSPARSE; ++f) {
        int v = __shfl(myI, f, 64);
        const float* e = emb2 + (size_t)v * EMBD;
        float e0 = e[l], e1 = e[l + 64];
        s0 += e0; ss0 += e0 * e0;
        s1 += e1; ss1 += e1 * e1;
    }
#pragma unroll
    for (int j = 0; j < 8; ++j) acc8[j] += __shfl_xor(acc8[j], 32, 64);
    if (half == 0) {
        ushort8 o;
#pragma unroll
        for (int j = 0; j < 8; ++j) o[j] = f32_bf16(fmaxf(acc8[j], 0.f));
        *(ushort8*)(h1b + (size_t)b * HID + li * 8) = o;
    }
    float r = 0.5f * ((s0 * s0 - ss0) + (s1 * s1 - ss1));
    if (l < NDENSE)  r += dense[b * NDENSE + l] * fm_w[l];
    if (l < NSPARSE) r += emb1[myI];
#pragma unroll
    for (int o = 32; o; o >>= 1) r += __shfl_xor(r, o, 64);
    if (l == 0) y12[b] = r;
}

// ---------------------------------------------------------------------------
// final: out[b] = sigmoid(y12[b] + h2[b,:].w3)
// ---------------------------------------------------------------------------
__global__ __launch_bounds__(256) void final_kernel(
    const ushort_t* __restrict__ h2b, const float* __restrict__ w3,
    const float* __restrict__ y12, float* __restrict__ out) {
    int b = blockIdx.x * 4 + (threadIdx.x >> 6);
    int lane = threadIdx.x & 63;
    const ushort_t* hr = h2b + (size_t)b * HID;
    float a = bf16_f32(hr[lane])       * w3[lane]
            + bf16_f32(hr[lane + 64])  * w3[lane + 64]
            + bf16_f32(hr[lane + 128]) * w3[lane + 128]
            + bf16_f32(hr[lane + 192]) * w3[lane + 192];
#pragma unroll
    for (int o = 32; o; o >>= 1) a += __shfl_xor(a, o, 64);
    if (lane == 0) {
        float z = y12[b] + a;
        out[b] = 1.f / (1.f + __expf(-z));
    }
}

// ---------------------------------------------------------------------------
extern "C" void kernel_launch(void* const* d_in, const int* in_sizes, int n_in,
                              void* d_out, int out_size, void* d_ws, size_t ws_size,
                              hipStream_t stream) {
    const float* dense = (const float*)d_in[0];
    const int*   sidx  = (const int*)d_in[1];
    const float* emb1  = (const float*)d_in[2];
    const float* emb2  = (const float*)d_in[3];
    const float* fm_w  = (const float*)d_in[4];
    const float* w1    = (const float*)d_in[5];
    const float* w2    = (const float*)d_in[6];
    const float* w3    = (const float*)d_in[7];
    float* out = (float*)d_out;

    // workspace carve (256B-aligned), ~84 MB total
    char* p = (char*)d_ws;
    auto carve = [&](size_t bytes) { void* r = (void*)p; p += (bytes + 255) & ~(size_t)255; return r; };
    ushort_t* e2b = (ushort_t*)carve((size_t)PAD_V * EMBD * 2);
    ushort_t* b1b = (ushort_t*)carve((size_t)NP * EMBD * 2);
    ushort_t* w2b = (ushort_t*)carve((size_t)HID * HID * 2);
    ushort_t* h1b = (ushort_t*)carve((size_t)B_ROWS * HID * 2);
    ushort_t* h2b = (ushort_t*)carve((size_t)B_ROWS * HID * 2);
    float*    y12 = (float*)carve((size_t)B_ROWS * 4);
    ushort_t* Pb  = (ushort_t*)carve((size_t)PAD_V * NP * 2);

    int n4;
    n4 = VOCAB * EMBD / 4;   // real rows only; pad rows stay 0xAA garbage (tiny, never gathered)
    split_kernel<<<(n4 + 255) / 256, 256, 0, stream>>>(emb2, e2b, n4);
    n4 = NP * EMBD / 4;
    splitT_kernel<<<(n4 + 255) / 256, 256, 0, stream>>>(w1, b1b, n4);
    n4 = HID * HID / 4;
    split_kernel<<<(n4 + 255) / 256, 256, 0, stream>>>(w2, w2b, n4);

    // P = emb2 @ B''^T   [4864 x 6656] bf16
    gemm_bf16_kernel<EMBD, false><<<dim3(PAD_V / 128, NP / 128), 256, 0, stream>>>(
        e2b, b1b, Pb, NP);

    // h1 = relu(gather-sum(P)), y12 = FM
    gather_fm_kernel<<<B_ROWS / 4, 256, 0, stream>>>(
        Pb, dense, sidx, emb1, emb2, fm_w, h1b, y12);

    // h2 = relu(h1 @ w2^T)
    gemm_bf16_kernel<HID, true><<<dim3(B_ROWS / 128, HID / 128), 256, 0, stream>>>(
        h1b, w2b, h2b, HID);

    final_kernel<<<B_ROWS / 4, 256, 0, stream>>>(h2b, w3, y12, out);
}

// Round 5
// 139.129 us; speedup vs baseline: 1.8274x; 1.0971x over previous
//
#include <hip/hip_runtime.h>
#include <cstdint>
#include <cstddef>

// DeepFM Criteo forward, MI355X/gfx950 — round 5 (round-4 resubmit + sI fix).
//   prep   : emb2,w1(permuted),w2 -> bf16 (one kernel)
//   gemm_p : P2[f][v][h] = emb2 @ B''^T  (4864x6656x128, single-shot K, bf16 out)
//   mega   : per 16 rows: gather-sum P2 (f-outer) -> h1 in LDS
//            + FM (y1+y2, fp32 arithmetic on bf16 emb2) + gemm2 (MFMA from LDS)
//            + w3 dot + sigmoid. h1/h2 never touch global memory.

#define B_ROWS   16384
#define NSPARSE  26
#define NDENSE   13
#define EMBD     128
#define HID      256
#define K1       (NSPARSE*EMBD)   // 3328
#define VOCAB    4823
#define PAD_V    4864             // 38*128
#define NP       (NSPARSE*HID)    // 6656

typedef unsigned short ushort_t;
typedef __attribute__((ext_vector_type(8))) short bf16x8;            // MFMA A/B frag
typedef __attribute__((ext_vector_type(8))) unsigned short ushort8;
typedef __attribute__((ext_vector_type(4))) float f32x4;             // MFMA C/D frag

__device__ __forceinline__ ushort_t f32_bf16(float x) {
    unsigned u = __builtin_bit_cast(unsigned, x);
    u += 0x7fffu + ((u >> 16) & 1u);
    return (ushort_t)(u >> 16);
}
__device__ __forceinline__ float bf16_f32(ushort_t h) {
    return __builtin_bit_cast(float, ((unsigned)h) << 16);
}

// async global->LDS, 16B/lane; LDS dest = wave-uniform base + lane*16 (linear).
__device__ __forceinline__ void gl2lds16(const void* g, void* l) {
    __builtin_amdgcn_global_load_lds(
        (const __attribute__((address_space(1))) void*)g,
        (__attribute__((address_space(3))) void*)l, 16, 0, 0);
}

// ---------------------------------------------------------------------------
// prep: all fp32->bf16 conversions in one launch.
//   seg A: emb2 -> e2b                                  (straight)
//   seg B: w1[h, f*128+d] -> b1b[(f*256+h)*128+d]       (permute)
//   seg C: w2 -> w2b                                    (straight)
// ---------------------------------------------------------------------------
__global__ __launch_bounds__(256) void prep_kernel(
    const float* __restrict__ emb2, const float* __restrict__ w1,
    const float* __restrict__ w2, ushort_t* __restrict__ e2b,
    ushort_t* __restrict__ b1b, ushort_t* __restrict__ w2b) {
    constexpr int NA = VOCAB * EMBD / 4;   // 154336
    constexpr int NB = NP * EMBD / 4;      // 212992
    constexpr int NC = HID * HID / 4;      // 16384
    int i = blockIdx.x * 256 + threadIdx.x;
    float4 x;
    ushort_t* dst;
    int di;
    if (i < NA) {
        x = ((const float4*)emb2)[i]; dst = e2b; di = i;
    } else if (i < NA + NB) {
        int j = i - NA;
        int c = j & 31, rowp = j >> 5;
        int f = rowp >> 8, h = rowp & 255;
        x = ((const float4*)w1)[h * (K1 / 4) + f * 32 + c];
        dst = b1b; di = j;
    } else if (i < NA + NB + NC) {
        int j = i - NA - NB;
        x = ((const float4*)w2)[j]; dst = w2b; di = j;
    } else return;
    union { ushort_t u[4]; uint2 v; } H;
    float xs[4] = {x.x, x.y, x.z, x.w};
#pragma unroll
    for (int j = 0; j < 4; ++j) H.u[j] = f32_bf16(xs[j]);
    ((uint2*)dst)[di] = H.v;
}

// ---------------------------------------------------------------------------
// gemm_p: P2[(f*PAD_V + v)*HID + h] = sum_d e2b[v,d] * b1b[f*256+h, d]
// 128x128 tile, K=128 single-shot (no K-loop, no double buffer): one stage of
// A+B (64 KB LDS, granule-XOR swizzle g ^= row&7 applied on global source and
// ds_read addr — involution), one barrier, 64 MFMA/wave, LDS-transpose epilogue.
// ---------------------------------------------------------------------------
__global__ __launch_bounds__(256) void gemm_p_kernel(
    const ushort_t* __restrict__ A, const ushort_t* __restrict__ Bm,
    ushort_t* __restrict__ P2) {
    __shared__ union {
        struct { ushort_t a[128 * 128]; ushort_t b[128 * 128]; } s;  // 64 KB
        ushort_t t[128 * 128];                                       // 32 KB
    } sm;
    const int tid = threadIdx.x;
    const int bm = blockIdx.x, bn = blockIdx.y;
    const int lane = tid & 63, wv = tid >> 6;

    // stage: 2048 16B-slots per operand; slot s holds data granule (s&15)^(row&7)
#pragma unroll
    for (int i = 0; i < 8; ++i) {
        int s = (wv * 8 + i) * 64 + lane;
        int row = s >> 4, g = s & 15;
        int gs = g ^ (row & 7);
        gl2lds16(A  + (size_t)(bm * 128 + row) * EMBD + gs * 8, &sm.s.a[s * 8]);
        gl2lds16(Bm + (size_t)(bn * 128 + row) * EMBD + gs * 8, &sm.s.b[s * 8]);
    }
    __syncthreads();   // drains vmcnt

    const int wr = wv >> 1, wc = wv & 1;
    const int lrow = lane & 15, lq = lane >> 4;
    f32x4 acc[4][4] = {};
#pragma unroll
    for (int ks = 0; ks < 4; ++ks) {
        bf16x8 af[4], bf[4];
#pragma unroll
        for (int m = 0; m < 4; ++m) {
            int row = wr * 64 + m * 16 + lrow;
            int g = (ks * 4 + lq) ^ (row & 7);
            af[m] = *(const bf16x8*)&sm.s.a[row * 128 + g * 8];
        }
#pragma unroll
        for (int n = 0; n < 4; ++n) {
            int row = wc * 64 + n * 16 + lrow;
            int g = (ks * 4 + lq) ^ (row & 7);
            bf[n] = *(const bf16x8*)&sm.s.b[row * 128 + g * 8];
        }
#pragma unroll
        for (int m = 0; m < 4; ++m)
#pragma unroll
            for (int n = 0; n < 4; ++n)
                acc[m][n] = __builtin_amdgcn_mfma_f32_16x16x32_bf16(af[m], bf[n], acc[m][n], 0, 0, 0);
    }
    __syncthreads();   // all ds_reads done before t overwrites a[]

    // epilogue: frag (col=lane&15, row=(lane>>4)*4+reg) -> LDS -> 16B stores
#pragma unroll
    for (int m = 0; m < 4; ++m)
#pragma unroll
        for (int n = 0; n < 4; ++n) {
            int col = wc * 64 + n * 16 + lrow;
#pragma unroll
            for (int r = 0; r < 4; ++r) {
                int row = wr * 64 + m * 16 + lq * 4 + r;
                sm.t[row * 128 + col] = f32_bf16(acc[m][n][r]);
            }
        }
    __syncthreads();
    const int f0 = bn >> 1, half = bn & 1;
    const int r0 = tid >> 4, c16 = tid & 15;
#pragma unroll
    for (int k = 0; k < 8; ++k) {
        int row = r0 + k * 16;
        ushort8 v8 = *(const ushort8*)&sm.t[row * 128 + c16 * 8];
        *(ushort8*)&P2[((size_t)f0 * PAD_V + bm * 128 + row) * HID + half * 128 + c16 * 8] = v8;
    }
}

// ---------------------------------------------------------------------------
// mega: 16 rows per block (grid 1024). Thread (row=t>>4, h16=t&15).
//  B: f-outer gather: hacc[16] (h = h16*16..+15) += P2[f][v]; FM s8/ss from e2b.
//  C: h1 -> LDS bf16 [16][264] (pad => 2-way conflict = free); gemm2 MFMA,
//     A-frag from LDS, B-frag (w2b) straight from global (L2-resident).
//  D: y3 = w3 . relu(h2) reduced in-wave; out = sigmoid(y12 + y3).
// ---------------------------------------------------------------------------
#define H1LD 264
__global__ __launch_bounds__(256) void mega_kernel(
    const ushort_t* __restrict__ P2, const ushort_t* __restrict__ e2b,
    const ushort_t* __restrict__ w2b, const float* __restrict__ dense,
    const int* __restrict__ sidx, const float* __restrict__ emb1,
    const float* __restrict__ fm_w, const float* __restrict__ w3,
    float* __restrict__ out) {
    __shared__ int      sI[16 * NSPARSE];
    __shared__ ushort_t h1s[16 * H1LD];
    __shared__ float    y12s[16];
    __shared__ float    y3s[4][16];

    const int tid = threadIdx.x;
    const int b0 = blockIdx.x * 16;
    // FIX (round 5): 416 entries, 256 threads -> strided loop (was `if (tid<416)`,
    // which left rows >=10 with poison indices -> OOB gathers).
    for (int i = tid; i < 16 * NSPARSE; i += 256) sI[i] = sidx[b0 * NSPARSE + i];
    __syncthreads();

    const int row = tid >> 4, h16 = tid & 15;
    float hacc[16] = {};
    float s8[8] = {};
    float ss = 0.f;
#pragma unroll 4
    for (int f = 0; f < NSPARSE; ++f) {
        int v = sI[row * NSPARSE + f];
        const ushort_t* pp = P2 + ((size_t)f * PAD_V + v) * HID + h16 * 16;
        ushort8 p0 = *(const ushort8*)pp;
        ushort8 p1 = *(const ushort8*)(pp + 8);
        ushort8 ev = *(const ushort8*)(e2b + (size_t)v * EMBD + h16 * 8);
#pragma unroll
        for (int j = 0; j < 8; ++j) {
            hacc[j]     += bf16_f32(p0[j]);
            hacc[8 + j] += bf16_f32(p1[j]);
            float e = bf16_f32(ev[j]);
            s8[j] += e; ss += e * e;
        }
    }
    // h1 -> LDS (relu, bf16)
    {
        union { ushort_t u[8]; ushort8 v; } o0, o1;
#pragma unroll
        for (int j = 0; j < 8; ++j) {
            o0.u[j] = f32_bf16(fmaxf(hacc[j], 0.f));
            o1.u[j] = f32_bf16(fmaxf(hacc[8 + j], 0.f));
        }
        *(ushort8*)&h1s[row * H1LD + h16 * 16]     = o0.v;
        *(ushort8*)&h1s[row * H1LD + h16 * 16 + 8] = o1.v;
    }
    // FM: y2 = 0.5*(sum_d s^2 - ss); y1 = dense.fm_w + sum emb1  (reduce over h16)
    float part = 0.f;
#pragma unroll
    for (int j = 0; j < 8; ++j) part += s8[j] * s8[j];
    part = 0.5f * (part - ss);
    if (h16 < NDENSE) {
        part += dense[(b0 + row) * NDENSE + h16] * fm_w[h16];
        part += emb1[sI[row * NSPARSE + h16]] + emb1[sI[row * NSPARSE + 13 + h16]];
    }
#pragma unroll
    for (int o = 8; o; o >>= 1) part += __shfl_xor(part, o, 64);
    if (h16 == 0) y12s[row] = part;
    __syncthreads();

    // gemm2: wave wv -> n-slice [wv*64, +64); M-tile = the block's 16 rows
    const int lane = tid & 63, wv = tid >> 6;
    const int lrow = lane & 15, lq = lane >> 4;
    f32x4 acc[4] = {};
#pragma unroll
    for (int ks = 0; ks < 8; ++ks) {
        bf16x8 af = *(const bf16x8*)&h1s[lrow * H1LD + ks * 32 + lq * 8];
#pragma unroll
        for (int nt = 0; nt < 4; ++nt) {
            bf16x8 bf = *(const bf16x8*)&w2b[(size_t)(wv * 64 + nt * 16 + lrow) * HID + ks * 32 + lq * 8];
            acc[nt] = __builtin_amdgcn_mfma_f32_16x16x32_bf16(af, bf, acc[nt], 0, 0, 0);
        }
    }
    // y3: lane holds h2[row=lq*4+r, n=wv*64+nt*16+lrow]
    float y3p[4] = {};
#pragma unroll
    for (int nt = 0; nt < 4; ++nt) {
        float wv3 = w3[wv * 64 + nt * 16 + lrow];
#pragma unroll
        for (int r = 0; r < 4; ++r) y3p[r] += fmaxf(acc[nt][r], 0.f) * wv3;
    }
#pragma unroll
    for (int r = 0; r < 4; ++r)
#pragma unroll
        for (int o = 8; o; o >>= 1) y3p[r] += __shfl_xor(y3p[r], o, 64);
    if (lrow == 0)
#pragma unroll
        for (int r = 0; r < 4; ++r) y3s[wv][lq * 4 + r] = y3p[r];
    __syncthreads();
    if (tid < 16) {
        float z = y12s[tid] + y3s[0][tid] + y3s[1][tid] + y3s[2][tid] + y3s[3][tid];
        out[b0 + tid] = 1.f / (1.f + __expf(-z));
    }
}

// ---------------------------------------------------------------------------
extern "C" void kernel_launch(void* const* d_in, const int* in_sizes, int n_in,
                              void* d_out, int out_size, void* d_ws, size_t ws_size,
                              hipStream_t stream) {
    const float* dense = (const float*)d_in[0];
    const int*   sidx  = (const int*)d_in[1];
    const float* emb1  = (const float*)d_in[2];
    const float* emb2  = (const float*)d_in[3];
    const float* fm_w  = (const float*)d_in[4];
    const float* w1    = (const float*)d_in[5];
    const float* w2    = (const float*)d_in[6];
    const float* w3    = (const float*)d_in[7];
    float* out = (float*)d_out;

    // workspace carve (256B-aligned), ~68 MB
    char* p = (char*)d_ws;
    auto carve = [&](size_t bytes) { void* r = (void*)p; p += (bytes + 255) & ~(size_t)255; return r; };
    ushort_t* e2b = (ushort_t*)carve((size_t)PAD_V * EMBD * 2);
    ushort_t* b1b = (ushort_t*)carve((size_t)NP * EMBD * 2);
    ushort_t* w2b = (ushort_t*)carve((size_t)HID * HID * 2);
    ushort_t* P2  = (ushort_t*)carve((size_t)NSPARSE * PAD_V * HID * 2);

    constexpr int NPREP = (VOCAB * EMBD + NP * EMBD + HID * HID) / 4;  // 383712
    prep_kernel<<<(NPREP + 255) / 256, 256, 0, stream>>>(emb2, w1, w2, e2b, b1b, w2b);

    gemm_p_kernel<<<dim3(PAD_V / 128, NP / 128), 256, 0, stream>>>(e2b, b1b, P2);

    mega_kernel<<<B_ROWS / 16, 256, 0, stream>>>(
        P2, e2b, w2b, dense, sidx, emb1, fm_w, w3, out);
}